// Round 5
// baseline (497.414 us; speedup 1.0000x reference)
//
#include <hip/hip_runtime.h>

#define BB 2
#define HH 1024
#define WW 1024
#define MU 5

// fused-pass tile geometry (trimmed to 78 staged tang cols for LDS margin)
#define TH 32
#define TW 64
#define SH (TH + 2 * MU)   // 42 staged rows
#define TCW 78             // tang staged cols: px w0-6 .. w0+71 (halo 6/8)
#define TST (TCW * 2)      // tang LDS row stride in floats (156)
#define SMS 81             // em LDS row stride (80 cols, odd stride -> conflict-free)
#define SVS 79             // V-result LDS row stride (odd -> conflict-free H reads)
#define LDSF (SH * TST + SH * SMS)   // 6552 + 3402 = 9954 floats = 39816 B

__device__ __forceinline__ float fast_rcp(float x) { return __builtin_amdgcn_rcpf(x); }
__device__ __forceinline__ float fast_rsq(float x) { return __builtin_amdgcn_rsqf(x); }

// ---------------------------------------------------------------------------
// Grid barrier: monotone device-scope counter (zeroed per launch by a 64B
// hipMemsetAsync -> no sense-reversal, no graph-replay state hazard).
// AGENT-scope acq_rel/acquire = the primitive ROCm grid.sync lowers to
// (cross-XCD L2 visibility). Bounded spin: on (impossible) residency failure
// we proceed and fail absmax finitely instead of hanging the container.
// Residency proof: LDS 39832B -> 78 x 512B granules; 4 x 39936 = 159744 <
// 160KiB; __launch_bounds__(256,4) caps VGPR<=128 -> 4 blocks/CU guaranteed;
// grid 1024 = 256 CU x 4 exactly co-resident.
// ---------------------------------------------------------------------------
__device__ __forceinline__ void gridbar(unsigned* cnt, unsigned target, int t)
{
    __syncthreads();               // all block stores issued (vmcnt drained)
    if (t == 0) {
        __hip_atomic_fetch_add(cnt, 1u, __ATOMIC_ACQ_REL, __HIP_MEMORY_SCOPE_AGENT);
        int spins = 0;
        while (__hip_atomic_load(cnt, __ATOMIC_ACQUIRE, __HIP_MEMORY_SCOPE_AGENT) < target) {
            __builtin_amdgcn_s_sleep(2);
            if (++spins > (1 << 22)) break;   // safety valve
        }
    }
    __syncthreads();
}

// ---------------------------------------------------------------------------
// One ETF V+H pass (proven compute structure, bit-identical numerics; s2
// hoisted). Weight identity: (tanh(my-mx)+1)/2 == 1/(1 + em_y/em_x),
// em = exp(-2*mag/gmax). OOB: tang=0, em=1 (exact reference zero-pad).
// Staged pixel ranges identical to the 131us kernel (tang cols w0-5..w0+68
// used; storage starts at w0-6 instead of w0-8).
// ---------------------------------------------------------------------------
template <int PLANAR>
__device__ __forceinline__ void etf_pass(
    float* __restrict__ lds,
    const float* __restrict__ tb,    // tin + 2*b*plane (interleaved)
    const float* __restrict__ mb,    // mag + b*plane (raw)
    float* __restrict__ o0,          // interleaved out, or planar plane 0
    float* __restrict__ o1,          // planar plane 1 (PLANAR only)
    float s2, int t, int w0, int h0)
{
    float* st  = lds;                 // staged tang, float2/px, row stride TST
    float* sm  = lds + SH * TST;      // staged em, row stride SMS
    float* sv0 = lds;                 // V results plane 0 (aliases st)
    float* sv1 = lds + TH * SVS;      // V results plane 1

    // ---- stage: tang 42x39 float4 (2px); em 42x20 float4 (4px) + exp
    for (int i = t; i < SH * 39 + SH * 20; i += 256) {
        if (i < SH * 39) {
            int r = i / 39, c4 = i % 39;
            int g = h0 - MU + r;
            int gw = w0 - 6 + 2 * c4;                  // even -> 16B-aligned
            float4 v = make_float4(0.f, 0.f, 0.f, 0.f);
            if (g >= 0 && g < HH && gw >= 0 && gw < WW)
                v = *(const float4*)(tb + 2 * ((size_t)g * WW + gw));
            *(float4*)&st[r * TST + 4 * c4] = v;
        } else {
            int j = i - SH * 39;
            int r = j / 20, c4 = j % 20;
            int g = h0 - MU + r;
            int gw = w0 - 8 + 4 * c4;                  // mult of 4 -> 16B-aligned
            float4 v = make_float4(0.f, 0.f, 0.f, 0.f);   // mag=0 -> em=1
            if (g >= 0 && g < HH && gw >= 0 && gw < WW)
                v = *(const float4*)(mb + (size_t)g * WW + gw);
            float* dst = &sm[r * SMS + 4 * c4];
            dst[0] = __expf(-s2 * v.x);
            dst[1] = __expf(-s2 * v.y);
            dst[2] = __expf(-s2 * v.z);
            dst[3] = __expf(-s2 * v.w);
        }
    }
    __syncthreads();

    // ---- shared register window (reused by V then H phase)
    float r0a[21], r1a[21], rea[21];

    // ---- V phase: 234 threads = 78 cols x 3 row-strips {11,11,10}.
    // tang col c <-> px (w0-6+c) <-> em col (c+2).
    const int c = t % TCW;
    const int strip = t / TCW;
    const int vr0row = strip * 11;
    const int Rv = (strip == 2) ? 10 : 11;
    if (t < 3 * TCW) {
        #pragma unroll
        for (int j = 0; j < 21; ++j) {
            if (j < Rv + 10) {
                float2 v = *(const float2*)&st[(vr0row + j) * TST + 2 * c];
                r0a[j] = v.x; r1a[j] = v.y;
                rea[j] = sm[(vr0row + j) * SMS + c + 2];
            }
        }
    }
    __syncthreads();          // all st reads done; safe to overwrite via sv alias

    __builtin_amdgcn_s_setprio(1);
    if (t < 3 * TCW) {
        #pragma unroll
        for (int i = 0; i < 11; ++i) {
            if (i < Rv) {
                float tx0 = r0a[i + 5], tx1 = r1a[i + 5];
                float remx = fast_rcp(rea[i + 5]);
                float a0 = 0.f, a1 = 0.f;
                #pragma unroll
                for (int d = 0; d <= 2 * MU; ++d) {
                    float y0 = r0a[i + d], y1 = r1a[i + d], ey = rea[i + d];
                    float s = fast_rcp(fmaf(ey, remx, 1.f));    // (tanh(my-mx)+1)/2
                    float w = s * fmaf(tx0, y0, tx1 * y1);
                    a0 = fmaf(y0, w, a0);
                    a1 = fmaf(y1, w, a1);
                }
                float n2 = fmaf(a0, a0, a1 * a1);
                float inv = (n2 == 0.f) ? 1.f : fast_rsq(n2);
                sv0[(vr0row + i) * SVS + c] = a0 * inv;
                sv1[(vr0row + i) * SVS + c] = a1 * inv;
            }
        }
    }
    __builtin_amdgcn_s_setprio(0);
    __syncthreads();

    // ---- H phase: r = t&31, colgroup = t>>5 of 8 cols; center col of
    // output col (cg*8+k) is staged col (6+cg*8+k).
    const int r = t & 31;
    const int cg_ = t >> 5;
    const int cbase = 6 + cg_ * 8;
    #pragma unroll
    for (int j = 0; j < 18; ++j) {
        int sc = cbase - 5 + j;              // 1..74: always in [0,TCW)
        r0a[j] = sv0[r * SVS + sc];
        r1a[j] = sv1[r * SVS + sc];
        rea[j] = sm[(r + MU) * SMS + sc + 2];
    }
    __syncthreads();          // all sv reads done; safe to overwrite below

    __builtin_amdgcn_s_setprio(1);
    #pragma unroll
    for (int k = 0; k < 8; ++k) {
        float tx0 = r0a[k + 5], tx1 = r1a[k + 5];
        float remx = fast_rcp(rea[k + 5]);
        float a0 = 0.f, a1 = 0.f;
        #pragma unroll
        for (int d = 0; d <= 2 * MU; ++d) {
            float y0 = r0a[k + d], y1 = r1a[k + d], ey = rea[k + d];
            float s = fast_rcp(fmaf(ey, remx, 1.f));
            float w = s * fmaf(tx0, y0, tx1 * y1);
            a0 = fmaf(y0, w, a0);
            a1 = fmaf(y1, w, a1);
        }
        float n2 = fmaf(a0, a0, a1 * a1);
        float inv = (n2 == 0.f) ? 1.f : fast_rsq(n2);
        sv0[r * SVS + cbase + k] = a0 * inv;    // write to LDS (post-barrier)
        sv1[r * SVS + cbase + k] = a1 * inv;
    }
    __builtin_amdgcn_s_setprio(0);
    __syncthreads();

    // ---- coalesced global writeout (lanes along cols)
    #pragma unroll
    for (int m = 0; m < 8; ++m) {
        int px = t + 256 * m;
        int rr = px >> 6, cc = px & 63;
        float v0 = sv0[rr * SVS + 6 + cc];
        float v1 = sv1[rr * SVS + 6 + cc];
        size_t gi = (size_t)(h0 + rr) * WW + (w0 + cc);
        if (PLANAR) {
            o0[gi] = v0;
            o1[gi] = v1;
        } else {
            *(float2*)&o0[2 * gi] = make_float2(v0, v1);
        }
    }
}

// ---------------------------------------------------------------------------
// MEGA-KERNEL: sobel -> gridbar -> gmax(once) -> pass1 -> gridbar -> pass2
// -> gridbar -> pass3. One dispatch instead of 4: removes 3 launch gaps, 2
// redundant gmax prologues, and the sobel dispatch ramp.
// ---------------------------------------------------------------------------
__global__ __launch_bounds__(256, 4) void etf_all(
    const float* __restrict__ x,
    float* __restrict__ tfA,
    float* __restrict__ tfB,
    float* __restrict__ mag,
    float* __restrict__ block_max,
    unsigned* __restrict__ bar,
    float* __restrict__ out)
{
    __shared__ float lds[LDSF];
    __shared__ float smax[4];

    const int t = threadIdx.x;
    const int lin0 = blockIdx.x;
    // XCD-aware swizzle (measured neutral; kept for slab locality; bijective)
    const int lin = (lin0 & 7) * 128 + (lin0 >> 3);
    const int w0 = (lin & 15) * TW;
    const int h0 = ((lin >> 4) & 31) * TH;
    const int b  = lin >> 9;
    const size_t plane = (size_t)HH * WW;

    // ---------------- Phase S: sobel + init tangent on this 32x64 tile ----
    {
        float* xs = lds;                       // 34 rows x stride 76 = 2584 floats
        const float* xb = x + (size_t)b * plane;
        for (int i = t; i < 34 * 18; i += 256) {
            int r = i / 18, c4 = i % 18;
            int g = h0 - 1 + r;
            int gw = w0 - 4 + 4 * c4;
            float4 v = make_float4(0.f, 0.f, 0.f, 0.f);
            if (g >= 0 && g < HH && gw >= 0 && gw < WW)
                v = *(const float4*)(xb + (size_t)g * WW + gw);
            *(float4*)&xs[r * 76 + 4 * c4] = v;
        }
        __syncthreads();

        float lmax = 0.f;
        const int cc = t & 63;
        const int rr = t >> 6;
        const int c = cc + 4;
        float* mb_w = mag + (size_t)b * plane;
        float2* tA2 = (float2*)(tfA + 2 * (size_t)b * plane);
        #pragma unroll
        for (int k = 0; k < 8; ++k) {
            int row = rr * 8 + k;
            const float* rT = &xs[row * 76];
            const float* rM = rT + 76;
            const float* rB = rM + 76;
            float tl = rT[c - 1], tc = rT[c], tr = rT[c + 1];
            float ml = rM[c - 1],             mr = rM[c + 1];
            float bl = rB[c - 1], bc = rB[c], br = rB[c + 1];
            float s0 = (bl - tl) + 2.f * (bc - tc) + (br - tr);   // k
            float s1 = (tr - tl) + 2.f * (mr - ml) + (br - bl);   // k^T
            float m = sqrtf(fmaf(s0, s0, s1 * s1));
            float inv = (m == 0.f) ? 1.f : fast_rcp(m);
            size_t gi = (size_t)(h0 + row) * WW + (w0 + cc);
            mb_w[gi] = m;
            tA2[gi] = make_float2(-s1 * inv, s0 * inv);
            lmax = fmaxf(lmax, m);
        }
        #pragma unroll
        for (int off = 32; off; off >>= 1) lmax = fmaxf(lmax, __shfl_down(lmax, off, 64));
        if ((t & 63) == 0) smax[t >> 6] = lmax;
        __syncthreads();
        if (t == 0)
            block_max[lin0] = fmaxf(fmaxf(smax[0], smax[1]), fmaxf(smax[2], smax[3]));
    }
    gridbar(bar, 1024, t);

    // ---------------- gmax reduce ONCE; s2 persists across iterations ------
    float s2;
    {
        float m = fmaxf(fmaxf(block_max[t], block_max[t + 256]),
                        fmaxf(block_max[t + 512], block_max[t + 768]));
        #pragma unroll
        for (int off = 32; off; off >>= 1) m = fmaxf(m, __shfl_down(m, off, 64));
        if ((t & 63) == 0) smax[t >> 6] = m;
        __syncthreads();
        const float gm = fmaxf(fmaxf(smax[0], smax[1]), fmaxf(smax[2], smax[3]));
        s2 = 2.f * fast_rcp(gm);
    }
    __syncthreads();   // smax reads done before any LDS reuse below

    const float* mb = mag + (size_t)b * plane;
    float* tA = tfA + 2 * (size_t)b * plane;
    float* tB = tfB + 2 * (size_t)b * plane;

    // ---------------- 3 ETF iterations, ping-pong through global -----------
    etf_pass<0>(lds, tA, mb, tB, nullptr, s2, t, w0, h0);
    gridbar(bar, 2048, t);
    etf_pass<0>(lds, tB, mb, tA, nullptr, s2, t, w0, h0);
    gridbar(bar, 3072, t);
    etf_pass<1>(lds, tA, mb,
                out + (size_t)(2 * b) * plane,
                out + (size_t)(2 * b + 1) * plane,
                s2, t, w0, h0);
}

extern "C" void kernel_launch(void* const* d_in, const int* in_sizes, int n_in,
                              void* d_out, int out_size, void* d_ws, size_t ws_size,
                              hipStream_t stream)
{
    const float* x = (const float*)d_in[0];   // (2,1,1024,1024) fp32
    char* ws = (char*)d_ws;
    const size_t plane = (size_t)HH * WW;

    float* tfA     = (float*)ws;                                        // 16 MB interleaved
    float* tfB     = (float*)(ws + sizeof(float) * BB * 2 * plane);     // 16 MB interleaved
    float* mg      = (float*)(ws + sizeof(float) * BB * 4 * plane);     // 8 MB raw
    float* bmax    = (float*)(ws + sizeof(float) * BB * 5 * plane);     // 1024 floats
    unsigned* bar  = (unsigned*)(ws + sizeof(float) * (BB * 5 * plane + 1024));

    hipMemsetAsync(bar, 0, 64, stream);       // barrier counter := 0 each launch

    etf_all<<<dim3(1024), dim3(256), 0, stream>>>(x, tfA, tfB, mg, bmax, bar,
                                                  (float*)d_out);
}